// Round 20
// baseline (25.001 us; speedup 1.0000x reference)
//
#include <hip/hip_runtime.h>
#include <hip/hip_bf16.h>

#define BATCH 64
#define NADJ  512
#define F     128
#define CROP0 128
#define CROP1 384
#define CN    256
#define BN_EPS 1e-5f

typedef __attribute__((ext_vector_type(8))) short short8;
typedef __attribute__((ext_vector_type(4))) float f32x4;

__device__ __forceinline__ ushort f2bf(float x) {
  __hip_bfloat16 h = __float2bfloat16(x);  // RNE
  return *reinterpret_cast<ushort*>(&h);
}

__device__ __forceinline__ float bf2f(ushort u) {
  const unsigned v = (unsigned)u << 16;
  float f;
  __builtin_memcpy(&f, &v, 4);
  return f;
}

__device__ __forceinline__ short8 cvt8(const float4 a, const float4 b) {
  short8 r;
  r[0] = (short)f2bf(a.x); r[1] = (short)f2bf(a.y);
  r[2] = (short)f2bf(a.z); r[3] = (short)f2bf(a.w);
  r[4] = (short)f2bf(b.x); r[5] = (short)f2bf(b.y);
  r[6] = (short)f2bf(b.z); r[7] = (short)f2bf(b.w);
  return r;
}

// ---------------------------------------------------------------------------
// KA v20 — associativity flip: O = (adj · X) · W  instead of adj · (X·W).
// 256 blocks x 512 threads, 1 block/CU; block = (batch b, quarter qt),
// 4 blocks/batch on XCD (b&7). Both GEMMs are block-PRIVATE: zero redundant
// compute (was 4x S-redundancy), 48 MFMA/wave (was 96), 2 barriers (was 5),
// input staged once as X^T (no 4-chunk pipeline).
//   phase 1: T[n][i] = sum_m adj[n][m] X[m][i]   (A=adj regs, B=X^T LDS)
//   phase 2: O[n][f] = sum_i T[n][i] W[i][f]     (A=T LDS, B=W^T LDS)
// LDS: xt[128][280] 71680 + wt[128][136] 34816 + tt[64][136] 17408
//    = 123904 B. Strides audited: 16B-aligned b128, <=2-way banks.
// ---------------------------------------------------------------------------
__global__ __launch_bounds__(512, 1) void gcn_ka(
    const float* __restrict__ input, const float* __restrict__ adj,
    const float* __restrict__ W, const float* __restrict__ beta,
    float* __restrict__ out, ushort* __restrict__ Ocrop) {
  const int x = blockIdx.x & 7, y = blockIdx.x >> 3;
  const int b  = ((y >> 2) << 3) | x;  // batch
  const int qt = y & 3;                // quarter (64 n-rows)
  __shared__ ushort xt[128][280];  // X^T [i][m]
  __shared__ ushort wt[128][136];  // W^T [f][i]
  __shared__ ushort tt[64][136];   // T [n][i]
  const int tid = threadIdx.x;
  const int l = tid & 63, w = tid >> 6;
  const int lr = l & 15, lg = l >> 4;

  // ---- pre-issue adj A-operand: 16 x float4 (rows n0w+lr, all k=m) ----
  const int n0w = qt * 64 + (w & 3) * 16;  // this wave's 16 n-rows
  const int wh  = w >> 2;                  // wave half-id (i-half / f-half)
  const float* a0 =
      adj + ((size_t)b * NADJ + CROP0 + n0w + lr) * NADJ + CROP0;
  float4 xreg[16];
#pragma unroll
  for (int ks = 0; ks < 8; ++ks) {
    const int k0 = ks * 32 + lg * 8;
    xreg[2 * ks]     = *reinterpret_cast<const float4*>(&a0[k0]);
    xreg[2 * ks + 1] = *reinterpret_cast<const float4*>(&a0[k0 + 4]);
  }

  // ---- beta-fill non-crop rows of out (independent stores) ----
  {
    const int gid = blockIdx.x * 512 + tid;
#pragma unroll
    for (int q = 0; q < 4; ++q) {
      const int g2 = gid + q * 131072;
      const int c4 = (g2 & 31) * 4;
      const int rr = (g2 >> 5) & 255;
      const int bb = g2 >> 13;
      const int n  = rr < 128 ? rr : rr + 256;
      const float4 bv =
          *reinterpret_cast<const float4*>(&beta[(size_t)n * F + c4]);
      *reinterpret_cast<float4*>(&out[((size_t)bb * NADJ + n) * F + c4]) = bv;
    }
  }

  // ---- stage W^T [f][i] ----
  {
    const int i0 = tid & 63;
    const int fq = (tid >> 6) * 16;
#pragma unroll
    for (int ih = 0; ih < 2; ++ih) {
      const int i = i0 + ih * 64;
      const float* wr = &W[(size_t)i * F + fq];
      float4 v[4];
#pragma unroll
      for (int q = 0; q < 4; ++q)
        v[q] = reinterpret_cast<const float4*>(wr)[q];
#pragma unroll
      for (int q = 0; q < 4; ++q) {
        wt[fq + q * 4 + 0][i] = f2bf(v[q].x);
        wt[fq + q * 4 + 1][i] = f2bf(v[q].y);
        wt[fq + q * 4 + 2][i] = f2bf(v[q].z);
        wt[fq + q * 4 + 3][i] = f2bf(v[q].w);
      }
    }
  }

  // ---- stage X^T [i][m] (coalesced reads, 2-way-bank scalar writes) ----
  const float* inb = input + ((size_t)b * NADJ + CROP0) * F;
#pragma unroll
  for (int q = 0; q < 16; ++q) {
    const int idx = tid + q * 512;     // [0, 8192)
    const int m   = idx >> 5;          // 0..255
    const int c4  = (idx & 31) * 4;    // 0..124
    const float4 v =
        *reinterpret_cast<const float4*>(&inb[(size_t)m * F + c4]);
    xt[c4 + 0][m] = f2bf(v.x);
    xt[c4 + 1][m] = f2bf(v.y);
    xt[c4 + 2][m] = f2bf(v.z);
    xt[c4 + 3][m] = f2bf(v.w);
  }

  // ---- convert adj regs in the load-latency shadow ----
  short8 areg[8];
#pragma unroll
  for (int ks = 0; ks < 8; ++ks)
    areg[ks] = cvt8(xreg[2 * ks], xreg[2 * ks + 1]);

  __syncthreads();  // xt + wt visible

  // ---- phase 1: T = adj x X.  wave: 16 n-rows x 64 i (i-half wh) ----
  const int if0 = wh * 64;
  f32x4 accT[4] = {};
#pragma unroll
  for (int ks = 0; ks < 8; ++ks) {
    const int k0 = ks * 32 + lg * 8;
#pragma unroll
    for (int fi = 0; fi < 4; ++fi) {
      const short8 bv =
          *reinterpret_cast<const short8*>(&xt[if0 + fi * 16 + lr][k0]);
      accT[fi] = __builtin_amdgcn_mfma_f32_16x16x32_bf16(areg[ks], bv,
                                                         accT[fi], 0, 0, 0);
    }
  }
  // write T to tt[n][i]: D layout col(i)=lane&15, row(n)=4*lg+reg
  const int nloc = (w & 3) * 16;  // local n-base within block's 64
#pragma unroll
  for (int fi = 0; fi < 4; ++fi) {
    const int i = if0 + fi * 16 + lr;
#pragma unroll
    for (int r = 0; r < 4; ++r)
      tt[nloc + lg * 4 + r][i] = f2bf(accT[fi][r]);
  }
  __syncthreads();  // tt visible

  // ---- phase 2: O = T x W.  wave: same 16 n-rows x 64 f (f-half wh) ----
  const int f0 = wh * 64;
  f32x4 acc[4] = {};
#pragma unroll
  for (int ks = 0; ks < 4; ++ks) {
    const int k0 = ks * 32 + lg * 8;
    const short8 av =
        *reinterpret_cast<const short8*>(&tt[nloc + lr][k0]);
#pragma unroll
    for (int fi = 0; fi < 4; ++fi) {
      const short8 bv =
          *reinterpret_cast<const short8*>(&wt[f0 + fi * 16 + lr][k0]);
      acc[fi] =
          __builtin_amdgcn_mfma_f32_16x16x32_bf16(av, bv, acc[fi], 0, 0, 0);
    }
  }

  // ---- store Ocrop (bf16): col(f)=lane&15, row(n)=4*lg+reg ----
#pragma unroll
  for (int fi = 0; fi < 4; ++fi) {
    const int f = f0 + fi * 16 + lr;
    const int n = n0w + lg * 4;
#pragma unroll
    for (int r = 0; r < 4; ++r)
      Ocrop[((size_t)b * CN + n + r) * F + f] = f2bf(acc[fi][r]);
  }
}

// ---------------------------------------------------------------------------
// KB: BN stats + normalize crop rows (vectorized x4; bf16 in, fp32 out).
// ---------------------------------------------------------------------------
__global__ __launch_bounds__(256) void gcn_kb(
    const ushort* __restrict__ Ocrop, float* __restrict__ out,
    const float* __restrict__ gamma, const float* __restrict__ beta) {
  __shared__ f32x4 s_l[256], s2_l[256];
  __shared__ f32x4 m_l[32], r_l[32];
  const int tid = threadIdx.x;
  const int qq = tid & 31, bg = tid >> 5;
  const int j  = (blockIdx.x * 32 + qq) * 4;  // feature id nl*128+f, f%4==0
  const int nl = j >> 7, f = j & 127;
  const int nf = (CROP0 + nl) * F + f;
  const ushort* p = Ocrop + (size_t)j + (size_t)bg * 8 * CN * F;

  f32x4 x[8];
  f32x4 s = {0.f, 0.f, 0.f, 0.f}, s2 = {0.f, 0.f, 0.f, 0.f};
#pragma unroll
  for (int bb = 0; bb < 8; ++bb) {
    const ushort4 u =
        *reinterpret_cast<const ushort4*>(&p[(size_t)bb * CN * F]);
    f32x4 v;
    v[0] = bf2f(u.x); v[1] = bf2f(u.y); v[2] = bf2f(u.z); v[3] = bf2f(u.w);
    x[bb] = v;
    s += v;
    s2 += v * v;
  }
  s_l[tid]  = s;
  s2_l[tid] = s2;
  __syncthreads();
  if (tid < 32) {
    f32x4 ts = {0.f, 0.f, 0.f, 0.f}, ts2 = {0.f, 0.f, 0.f, 0.f};
#pragma unroll
    for (int g = 0; g < 8; ++g) {
      ts += s_l[g * 32 + tid];
      ts2 += s2_l[g * 32 + tid];
    }
    const f32x4 mean = ts * (1.f / BATCH);
    const f32x4 var  = ts2 * (1.f / BATCH) - mean * mean;
    f32x4 rs;
    rs[0] = rsqrtf(var[0] + BN_EPS);
    rs[1] = rsqrtf(var[1] + BN_EPS);
    rs[2] = rsqrtf(var[2] + BN_EPS);
    rs[3] = rsqrtf(var[3] + BN_EPS);
    m_l[tid] = mean;
    r_l[tid] = rs;
  }
  __syncthreads();
  const f32x4 mean = m_l[qq];
  const f32x4 rs   = r_l[qq];
  const float4 gm = *reinterpret_cast<const float4*>(&gamma[nf]);
  const float4 bt = *reinterpret_cast<const float4*>(&beta[nf]);
  f32x4 a, c;
  a[0] = rs[0] * gm.x; a[1] = rs[1] * gm.y;
  a[2] = rs[2] * gm.z; a[3] = rs[3] * gm.w;
  c[0] = bt.x - mean[0] * a[0]; c[1] = bt.y - mean[1] * a[1];
  c[2] = bt.z - mean[2] * a[2]; c[3] = bt.w - mean[3] * a[3];
#pragma unroll
  for (int bb = 0; bb < 8; ++bb) {
    const f32x4 yv = x[bb] * a + c;
    *reinterpret_cast<f32x4*>(
        &out[(size_t)nf + (size_t)(bg * 8 + bb) * NADJ * F]) = yv;
  }
}

extern "C" void kernel_launch(void* const* d_in, const int* in_sizes, int n_in,
                              void* d_out, int out_size, void* d_ws,
                              size_t ws_size, hipStream_t stream) {
  const float* input = (const float*)d_in[0];
  const float* adj   = (const float*)d_in[1];
  const float* W     = (const float*)d_in[2];
  const float* gamma = (const float*)d_in[3];
  const float* beta  = (const float*)d_in[4];
  float* out = (float*)d_out;

  ushort* Ocrop = (ushort*)d_ws;  // 64*256*128 bf16 = 4.2 MB

  gcn_ka<<<256, 512, 0, stream>>>(input, adj, W, beta, out, Ocrop);
  gcn_kb<<<256, 256, 0, stream>>>(Ocrop, out, gamma, beta);
}